// Round 1
// baseline (1408.142 us; speedup 1.0000x reference)
//
#include <hip/hip_runtime.h>
#include <hip/hip_bf16.h>
#include <stdint.h>

#define LAM0 1.0f
#define LAM1 1.0f
#define ALPHA_F (1.0f/3.0f)

typedef unsigned short u16;
typedef __attribute__((ext_vector_type(4))) float f32x4;
typedef __attribute__((ext_vector_type(8))) __bf16 bf16x8;

__device__ __forceinline__ u16 f2bfu(float f){
  union { __hip_bfloat16 h; u16 u; } cv;
  cv.h = __float2bfloat16(f);   // RNE
  return cv.u;
}

// async global->LDS, 16B per lane (wave-uniform base + lane*16 placement)
__device__ __forceinline__ void async16(u16* lds, const u16* g){
  __builtin_amdgcn_global_load_lds((const __attribute__((address_space(1))) void*)g,
                                   (__attribute__((address_space(3))) void*)lds, 16, 0, 0);
}

// ---------------- prep kernels ----------------
// BsT: 512 x 128 bf16, n-major "B^T" rows for U = Y @ [LAM0*S1 | LAM1*(S2-I) | P1 | P2]
__global__ void prep_bsmall(const float* __restrict__ H1, const float* __restrict__ H2,
                            u16* __restrict__ BsT){
  int np = blockIdx.x;       // 0..511
  int k  = threadIdx.x;      // 0..127
  float v;
  if (np < 128){
    v = LAM0*(H1[k*128+np] + H1[np*128+k]);
  } else if (np < 256){
    int j = np-128;
    v = LAM1*(H2[k*128+j] + H2[j*128+k] - (k==j ? 1.0f : 0.0f));
  } else if (np < 384){
    int j = np-256; float s = 0.f;
    for (int q=0;q<128;++q) s += H1[k*128+q]*H1[j*128+q];
    v = s;
  } else {
    int j = np-384; float s = 0.f;
    for (int q=0;q<128;++q) s += H2[k*128+q]*H2[j*128+q];
    v = s;
  }
  BsT[np*128+k] = f2bfu(v);
}

__global__ void qinv_kernel(const float* __restrict__ db, const float* __restrict__ dg,
                            float* __restrict__ q){
  int i = blockIdx.x*256 + threadIdx.x;
  if (i < 8192) q[i] = 1.0f/(LAM0*db[i] + LAM1*dg[i] + 1.0f);
}

__global__ void cast_simple(const float* __restrict__ s, u16* __restrict__ d, int n){
  int i = blockIdx.x*256 + threadIdx.x;
  if (i < n) d[i] = f2bfu(s[i]);
}

// Acat: 8192 x 16384 bf16, row i = [A_beta[i,:] | A_gamma[i,:]]
__global__ void cast_acat_kernel(const float* __restrict__ Ab, const float* __restrict__ Ag,
                                 u16* __restrict__ Acat){
  size_t o = ((size_t)blockIdx.x*256 + threadIdx.x)*8;
  size_t i = o >> 14;
  int k = (int)(o & 16383);
  const float* src = (k < 8192) ? (Ab + i*8192 + k) : (Ag + i*8192 + (k - 8192));
  f32x4 v0 = *(const f32x4*)src;
  f32x4 v1 = *(const f32x4*)(src + 4);
  ushort4 a, b;
  a.x = f2bfu(v0[0]); a.y = f2bfu(v0[1]); a.z = f2bfu(v0[2]); a.w = f2bfu(v0[3]);
  b.x = f2bfu(v1[0]); b.y = f2bfu(v1[1]); b.z = f2bfu(v1[2]); b.w = f2bfu(v1[3]);
  *(ushort4*)(Acat + o) = a;
  *(ushort4*)(Acat + o + 4) = b;
}

// ---------------- generic bf16 MFMA GEMM ----------------
// C(M x N) = A(M x K, bf16 row-major) @ B^T-rows(N x K, bf16 n-major), BK=64, XOR-swizzled
// LDS tiles staged via global_load_lds width-16.
// EPI 0: fp32 partial store, K-split chunk = blockIdx.z, out0 = partials
// EPI 1: relu(C + bias) -> out0 fp32 (ld 128) and outbf bf16 (ld 128)
// EPI 2: cols<256 -> outbf = UcatT (128 x 16384 bf16, transposed); cols>=256 -> out0 = UPf (8192 x 256 fp32)
template<int WM, int WN, int MT, int NT, int EPI>
__launch_bounds__(256, 2)
__global__ void gemm_bf16(const u16* __restrict__ A, int ldA,
                          const u16* __restrict__ B, int ldB,
                          int ksteps,
                          float* __restrict__ out0,
                          u16* __restrict__ outbf,
                          const float* __restrict__ bias){
  constexpr int BM = WM*MT*16;
  constexpr int BN = WN*NT*16;
  __shared__ u16 ldsA[BM*64];
  __shared__ u16 ldsB[BN*64];
  const int tid  = threadIdx.x;
  const int m0   = blockIdx.x * BM;
  const int n0   = blockIdx.y * BN;
  const int kch  = blockIdx.z;
  const int kbase = kch * ksteps * 64;
  const int wave = tid >> 6, lane = tid & 63;
  const int l15 = lane & 15, quad = lane >> 4;
  const int wm = wave / WN, wn = wave % WN;

  f32x4 acc[MT][NT];
  #pragma unroll
  for (int mt=0; mt<MT; ++mt)
    #pragma unroll
    for (int nt=0; nt<NT; ++nt)
      acc[mt][nt] = f32x4{0.f,0.f,0.f,0.f};

  #pragma unroll 1
  for (int it=0; it<ksteps; ++it){
    const int k0 = kbase + it*64;
    // stage A tile (BM x 64), dense rows of 128B, chunk-XOR swizzle
    #pragma unroll
    for (int r=0; r<BM/32; ++r){
      int cid = r*256 + tid;
      int row = cid >> 3, cph = cid & 7;
      int cgl = cph ^ (row & 7);
      async16(&ldsA[cid*8], A + (size_t)(m0+row)*ldA + (k0 + cgl*8));
    }
    // stage B tile (BN x 64)
    #pragma unroll
    for (int r=0; r<BN/32; ++r){
      int cid = r*256 + tid;
      int row = cid >> 3, cph = cid & 7;
      int cgl = cph ^ (row & 7);
      async16(&ldsB[cid*8], B + (size_t)(n0+row)*ldB + (k0 + cgl*8));
    }
    __syncthreads();   // compiler emits vmcnt(0) drain before barrier
    #pragma unroll
    for (int kk=0; kk<2; ++kk){
      bf16x8 af[MT], bg[NT];
      #pragma unroll
      for (int mt=0; mt<MT; ++mt){
        int am = wm*MT*16 + mt*16 + l15;
        int cph = (kk*4 + quad) ^ (am & 7);
        af[mt] = *(const bf16x8*)&ldsA[am*64 + cph*8];
      }
      #pragma unroll
      for (int nt=0; nt<NT; ++nt){
        int bn = wn*NT*16 + nt*16 + l15;
        int cph = (kk*4 + quad) ^ (bn & 7);
        bg[nt] = *(const bf16x8*)&ldsB[bn*64 + cph*8];
      }
      #pragma unroll
      for (int mt=0; mt<MT; ++mt)
        #pragma unroll
        for (int nt=0; nt<NT; ++nt)
          acc[mt][nt] = __builtin_amdgcn_mfma_f32_16x16x32_bf16(af[mt], bg[nt], acc[mt][nt], 0, 0, 0);
    }
    __syncthreads();
  }

  const int ibase = m0 + wm*MT*16;
  const int jbase = n0 + wn*NT*16;
  if constexpr (EPI == 0){
    float* outp = out0 + (size_t)kch * (8192*128);
    #pragma unroll
    for (int mt=0; mt<MT; ++mt){
      int i0 = ibase + mt*16 + quad*4;
      #pragma unroll
      for (int nt=0; nt<NT; ++nt){
        int j = jbase + nt*16 + l15;
        #pragma unroll
        for (int r=0; r<4; ++r)
          outp[(size_t)(i0+r)*128 + j] = acc[mt][nt][r];
      }
    }
  } else if constexpr (EPI == 1){
    #pragma unroll
    for (int mt=0; mt<MT; ++mt){
      int i0 = ibase + mt*16 + quad*4;
      #pragma unroll
      for (int nt=0; nt<NT; ++nt){
        int j = jbase + nt*16 + l15;
        float bj = bias[j];
        #pragma unroll
        for (int r=0; r<4; ++r){
          float v = acc[mt][nt][r] + bj;
          v = fmaxf(v, 0.0f);
          out0 [(size_t)(i0+r)*128 + j] = v;
          outbf[(size_t)(i0+r)*128 + j] = f2bfu(v);
        }
      }
    }
  } else {
    #pragma unroll
    for (int mt=0; mt<MT; ++mt){
      int i0 = ibase + mt*16 + quad*4;    // multiple of 4 -> 8B-aligned UcatT store
      #pragma unroll
      for (int nt=0; nt<NT; ++nt){
        int jg = jbase + nt*16 + l15;
        if (jg < 256){
          int nn = jg & 127;
          size_t koff = (jg < 128) ? (size_t)0 : (size_t)8192;
          ushort4 p;
          p.x = f2bfu(acc[mt][nt][0]);
          p.y = f2bfu(acc[mt][nt][1]);
          p.z = f2bfu(acc[mt][nt][2]);
          p.w = f2bfu(acc[mt][nt][3]);
          *(ushort4*)&outbf[(size_t)nn*16384 + koff + i0] = p;
        } else {
          #pragma unroll
          for (int r=0; r<4; ++r)
            out0[(size_t)(i0+r)*256 + (jg-256)] = acc[mt][nt][r];
        }
      }
    }
  }
}

// ---------------- per-step elementwise update ----------------
__global__ void step_update(const float* __restrict__ part, const float* __restrict__ Y,
                            const float* __restrict__ Y0, const float* __restrict__ UP,
                            const float* __restrict__ dbt, const float* __restrict__ dgt,
                            const float* __restrict__ qv,
                            float* __restrict__ Yn, u16* __restrict__ Ybn){
  int idx = blockIdx.x*256 + threadIdx.x;      // 262144 float4 groups
  int e = idx*4;
  int i = e >> 7, j = e & 127;
  f32x4 g = *(const f32x4*)(part + e);
  g += *(const f32x4*)(part + 1048576 + e);
  g += *(const f32x4*)(part + 2097152 + e);
  g += *(const f32x4*)(part + 3145728 + e);
  f32x4 y  = *(const f32x4*)(Y  + e);
  f32x4 y0 = *(const f32x4*)(Y0 + e);
  f32x4 u1 = *(const f32x4*)(UP + (size_t)i*256 + j);
  f32x4 u2 = *(const f32x4*)(UP + (size_t)i*256 + 128 + j);
  float db = LAM0*dbt[i], dg = LAM1*dgt[i], qi = qv[i];
  f32x4 yh = g + y0 + dg*y - (db*u1 + dg*u2);
  f32x4 yn = (1.0f-ALPHA_F)*y + (ALPHA_F*qi)*yh;
  *(f32x4*)(Yn + e) = yn;
  ushort4 pk;
  pk.x = f2bfu(yn[0]); pk.y = f2bfu(yn[1]); pk.z = f2bfu(yn[2]); pk.w = f2bfu(yn[3]);
  *(ushort4*)(Ybn + e) = pk;
}

// ---------------- classifier head: relu(Y) @ W2^T + b2 ----------------
__global__ void final_out(const float* __restrict__ Y, const float* __restrict__ W2,
                          const float* __restrict__ b2, float* __restrict__ out){
  int g = blockIdx.x*256 + threadIdx.x;
  if (g >= 8192*40) return;
  int i = g / 40, c = g - i*40;
  const float* yr = Y + (size_t)i*128;
  const float* wr = W2 + c*128;
  float s = 0.f;
  #pragma unroll 8
  for (int k=0; k<128; k+=4){
    f32x4 yv = *(const f32x4*)(yr+k);
    f32x4 wv = *(const f32x4*)(wr+k);
    s += fmaxf(yv[0],0.f)*wv[0] + fmaxf(yv[1],0.f)*wv[1]
       + fmaxf(yv[2],0.f)*wv[2] + fmaxf(yv[3],0.f)*wv[3];
  }
  out[g] = s + b2[c];
}

extern "C" void kernel_launch(void* const* d_in, const int* in_sizes, int n_in,
                              void* d_out, int out_size, void* d_ws, size_t ws_size,
                              hipStream_t stream){
  const float* x  = (const float*)d_in[0];
  const float* Ab = (const float*)d_in[1];
  const float* Ag = (const float*)d_in[2];
  const float* db = (const float*)d_in[3];
  const float* dg = (const float*)d_in[4];
  const float* H1 = (const float*)d_in[5];
  const float* H2 = (const float*)d_in[6];
  const float* W1 = (const float*)d_in[7];
  const float* b1 = (const float*)d_in[8];
  const float* W2 = (const float*)d_in[9];
  const float* b2 = (const float*)d_in[10];
  float* out = (float*)d_out;

  char* w = (char*)d_ws;
  size_t off = 0;
  auto take = [&](size_t bytes){ void* p = w + off; off += (bytes + 255) & ~(size_t)255; return p; };
  u16*   Acat  = (u16*)  take((size_t)8192*16384*2);   // 256 MiB
  u16*   UcatT = (u16*)  take((size_t)128*16384*2);    // 4 MiB
  float* UPf   = (float*)take((size_t)8192*256*4);     // 8 MiB
  float* part  = (float*)take((size_t)4*8192*128*4);   // 16 MiB
  float* Y0f   = (float*)take((size_t)8192*128*4);
  float* Ya    = (float*)take((size_t)8192*128*4);
  float* Yb    = (float*)take((size_t)8192*128*4);
  u16*   Ybf0  = (u16*)  take((size_t)8192*128*2);
  u16*   Ybfa  = (u16*)  take((size_t)8192*128*2);
  u16*   Ybfb  = (u16*)  take((size_t)8192*128*2);
  u16*   xbf   = (u16*)  take((size_t)8192*512*2);
  u16*   BsT   = (u16*)  take((size_t)512*128*2);
  u16*   W1bf  = (u16*)  take((size_t)128*512*2);
  float* qinv  = (float*)take((size_t)8192*4);
  if (off > ws_size) return;  // workspace too small -> fail visibly

  // ---- one-time prep ----
  prep_bsmall<<<512, 128, 0, stream>>>(H1, H2, BsT);
  qinv_kernel<<<32, 256, 0, stream>>>(db, dg, qinv);
  cast_simple<<<256, 256, 0, stream>>>(W1, W1bf, 128*512);
  cast_simple<<<16384, 256, 0, stream>>>(x, xbf, 8192*512);
  cast_acat_kernel<<<65536, 256, 0, stream>>>(Ab, Ag, Acat);

  // Y0 = relu(x @ W1^T + b1): M=8192,K=512,N=128; BM=32 -> 256 blocks
  gemm_bf16<1,4,2,2,1><<<dim3(256,1,1), 256, 0, stream>>>(xbf, 512, W1bf, 512, 8, Y0f, Ybf0, b1);

  const float* Yc = Y0f; const u16* Ybc = Ybf0;
  for (int s=0; s<8; ++s){
    // U = Y @ [S1'|S2'|P1|P2]: M=8192,K=128,N=512 (4 N-blocks)
    gemm_bf16<2,2,2,4,2><<<dim3(128,4,1), 256, 0, stream>>>(Ybc, 128, BsT, 128, 2, UPf, UcatT, nullptr);
    // G1+G2 = Acat @ Ucat: M=8192,K=16384,N=128, K-split 4
    gemm_bf16<2,2,2,4,0><<<dim3(128,1,4), 256, 0, stream>>>(Acat, 16384, UcatT, 16384, 64, part, nullptr, nullptr);
    float* Yn  = (s & 1) ? Yb   : Ya;
    u16*   Ybn = (s & 1) ? Ybfb : Ybfa;
    step_update<<<1024, 256, 0, stream>>>(part, Yc, Y0f, UPf, db, dg, qinv, Yn, Ybn);
    Yc = Yn; Ybc = Ybn;
  }
  final_out<<<1280, 256, 0, stream>>>(Yc, W2, b2, out);
}

// Round 2
// 968.739 us; speedup vs baseline: 1.4536x; 1.4536x over previous
//
#include <hip/hip_runtime.h>
#include <hip/hip_bf16.h>
#include <stdint.h>

#define LAM0 1.0f
#define LAM1 1.0f
#define ALPHA_F (1.0f/3.0f)

typedef unsigned short u16;
typedef unsigned char u8;
typedef __attribute__((ext_vector_type(4))) float f32x4;
typedef __attribute__((ext_vector_type(16))) float f32x16;
typedef __attribute__((ext_vector_type(8))) __bf16 bf16x8;
typedef __attribute__((ext_vector_type(8))) int i32x8;

__device__ __forceinline__ u16 f2bfu(float f){
  union { __hip_bfloat16 h; u16 u; } cv;
  cv.h = __float2bfloat16(f);   // RNE
  return cv.u;
}

// pack 4 floats -> 4 fp8 e4m3 bytes (HW cvt, RNE)
__device__ __forceinline__ unsigned int pk4_fp8(float a, float b, float c, float d){
  int w = 0;
  w = __builtin_amdgcn_cvt_pk_fp8_f32(a, b, w, false);  // bytes 0,1
  w = __builtin_amdgcn_cvt_pk_fp8_f32(c, d, w, true);   // bytes 2,3
  return (unsigned int)w;
}

// async global->LDS, 16B per lane (wave-uniform base + lane*16 placement)
__device__ __forceinline__ void async16(void* lds, const void* g){
  __builtin_amdgcn_global_load_lds((const __attribute__((address_space(1))) void*)g,
                                   (__attribute__((address_space(3))) void*)lds, 16, 0, 0);
}

// ---------------- prep kernels ----------------
// BsT: 512 x 128 bf16, n-major "B^T" rows for U = Y @ [LAM0*S1 | LAM1*(S2-I) | P1 | P2]
__global__ void prep_bsmall(const float* __restrict__ H1, const float* __restrict__ H2,
                            u16* __restrict__ BsT){
  int np = blockIdx.x;       // 0..511
  int k  = threadIdx.x;      // 0..127
  float v;
  if (np < 128){
    v = LAM0*(H1[k*128+np] + H1[np*128+k]);
  } else if (np < 256){
    int j = np-128;
    v = LAM1*(H2[k*128+j] + H2[j*128+k] - (k==j ? 1.0f : 0.0f));
  } else if (np < 384){
    int j = np-256; float s = 0.f;
    for (int q=0;q<128;++q) s += H1[k*128+q]*H1[j*128+q];
    v = s;
  } else {
    int j = np-384; float s = 0.f;
    for (int q=0;q<128;++q) s += H2[k*128+q]*H2[j*128+q];
    v = s;
  }
  BsT[np*128+k] = f2bfu(v);
}

__global__ void qinv_kernel(const float* __restrict__ db, const float* __restrict__ dg,
                            float* __restrict__ q){
  int i = blockIdx.x*256 + threadIdx.x;
  if (i < 8192) q[i] = 1.0f/(LAM0*db[i] + LAM1*dg[i] + 1.0f);
}

__global__ void cast_simple(const float* __restrict__ s, u16* __restrict__ d, int n){
  int i = blockIdx.x*256 + threadIdx.x;
  if (i < n) d[i] = f2bfu(s[i]);
}

// Acat8: 8192 x 16384 fp8, row i = [A_beta[i,:] | A_gamma[i,:]] * 2^16
__global__ void cast_acat8(const float* __restrict__ Ab, const float* __restrict__ Ag,
                           u8* __restrict__ Acat){
  size_t o = ((size_t)blockIdx.x*256 + threadIdx.x)*16;   // 16 elements per thread
  size_t i = o >> 14;
  int k = (int)(o & 16383);
  const float* src = (k < 8192) ? (Ab + i*8192 + k) : (Ag + i*8192 + (k - 8192));
  const float S = 65536.0f;
  uint4 pk;
  {
    f32x4 v0 = *(const f32x4*)(src +  0);
    f32x4 v1 = *(const f32x4*)(src +  4);
    f32x4 v2 = *(const f32x4*)(src +  8);
    f32x4 v3 = *(const f32x4*)(src + 12);
    pk.x = pk4_fp8(v0[0]*S, v0[1]*S, v0[2]*S, v0[3]*S);
    pk.y = pk4_fp8(v1[0]*S, v1[1]*S, v1[2]*S, v1[3]*S);
    pk.z = pk4_fp8(v2[0]*S, v2[1]*S, v2[2]*S, v2[3]*S);
    pk.w = pk4_fp8(v3[0]*S, v3[1]*S, v3[2]*S, v3[3]*S);
  }
  *(uint4*)(Acat + o) = pk;
}

// ---------------- generic bf16 MFMA GEMM (small GEMMs) ----------------
// EPI 1: relu(C + bias) -> out0 fp32 (ld 128) and outbf bf16 (ld 128)
// EPI 2: cols<256 -> out8 = Ucat8 (128 x 16384 fp8, transposed); cols>=256 -> out0 = UPf (8192 x 256 fp32)
template<int WM, int WN, int MT, int NT, int EPI>
__launch_bounds__(256, 2)
__global__ void gemm_bf16(const u16* __restrict__ A, int ldA,
                          const u16* __restrict__ B, int ldB,
                          int ksteps,
                          float* __restrict__ out0,
                          u16* __restrict__ outbf,
                          u8* __restrict__ out8,
                          const float* __restrict__ bias){
  constexpr int BM = WM*MT*16;
  constexpr int BN = WN*NT*16;
  __shared__ u16 ldsA[BM*64];
  __shared__ u16 ldsB[BN*64];
  const int tid  = threadIdx.x;
  const int m0   = blockIdx.x * BM;
  const int n0   = blockIdx.y * BN;
  const int wave = tid >> 6, lane = tid & 63;
  const int l15 = lane & 15, quad = lane >> 4;
  const int wm = wave / WN, wn = wave % WN;

  f32x4 acc[MT][NT];
  #pragma unroll
  for (int mt=0; mt<MT; ++mt)
    #pragma unroll
    for (int nt=0; nt<NT; ++nt)
      acc[mt][nt] = f32x4{0.f,0.f,0.f,0.f};

  #pragma unroll 1
  for (int it=0; it<ksteps; ++it){
    const int k0 = it*64;
    #pragma unroll
    for (int r=0; r<BM/32; ++r){
      int cid = r*256 + tid;
      int row = cid >> 3, cph = cid & 7;
      int cgl = cph ^ (row & 7);
      async16(&ldsA[cid*8], A + (size_t)(m0+row)*ldA + (k0 + cgl*8));
    }
    #pragma unroll
    for (int r=0; r<BN/32; ++r){
      int cid = r*256 + tid;
      int row = cid >> 3, cph = cid & 7;
      int cgl = cph ^ (row & 7);
      async16(&ldsB[cid*8], B + (size_t)(n0+row)*ldB + (k0 + cgl*8));
    }
    __syncthreads();
    #pragma unroll
    for (int kk=0; kk<2; ++kk){
      bf16x8 af[MT], bg[NT];
      #pragma unroll
      for (int mt=0; mt<MT; ++mt){
        int am = wm*MT*16 + mt*16 + l15;
        int cph = (kk*4 + quad) ^ (am & 7);
        af[mt] = *(const bf16x8*)&ldsA[am*64 + cph*8];
      }
      #pragma unroll
      for (int nt=0; nt<NT; ++nt){
        int bn = wn*NT*16 + nt*16 + l15;
        int cph = (kk*4 + quad) ^ (bn & 7);
        bg[nt] = *(const bf16x8*)&ldsB[bn*64 + cph*8];
      }
      #pragma unroll
      for (int mt=0; mt<MT; ++mt)
        #pragma unroll
        for (int nt=0; nt<NT; ++nt)
          acc[mt][nt] = __builtin_amdgcn_mfma_f32_16x16x32_bf16(af[mt], bg[nt], acc[mt][nt], 0, 0, 0);
    }
    __syncthreads();
  }

  const int ibase = m0 + wm*MT*16;
  const int jbase = n0 + wn*NT*16;
  if constexpr (EPI == 1){
    #pragma unroll
    for (int mt=0; mt<MT; ++mt){
      int i0 = ibase + mt*16 + quad*4;
      #pragma unroll
      for (int nt=0; nt<NT; ++nt){
        int j = jbase + nt*16 + l15;
        float bj = bias[j];
        #pragma unroll
        for (int r=0; r<4; ++r){
          float v = acc[mt][nt][r] + bj;
          v = fmaxf(v, 0.0f);
          out0 [(size_t)(i0+r)*128 + j] = v;
          outbf[(size_t)(i0+r)*128 + j] = f2bfu(v);
        }
      }
    }
  } else {
    #pragma unroll
    for (int mt=0; mt<MT; ++mt){
      int i0 = ibase + mt*16 + quad*4;    // multiple of 4 -> 4B-aligned Ucat8 store
      #pragma unroll
      for (int nt=0; nt<NT; ++nt){
        int jg = jbase + nt*16 + l15;
        if (jg < 256){
          int nn = jg & 127;
          size_t koff = (jg < 128) ? (size_t)0 : (size_t)8192;
          unsigned int pk = pk4_fp8(acc[mt][nt][0], acc[mt][nt][1], acc[mt][nt][2], acc[mt][nt][3]);
          *(unsigned int*)&out8[(size_t)nn*16384 + koff + i0] = pk;
        } else {
          #pragma unroll
          for (int r=0; r<4; ++r)
            out0[(size_t)(i0+r)*256 + (jg-256)] = acc[mt][nt][r];
        }
      }
    }
  }
}

// ---------------- big fp8 MX GEMM: part[kch] = (Acat8 @ Ucat8^T-rows) * 2^-16 ----------------
// A: 8192 x 16384 fp8 row-major; B: 128 x 16384 fp8 n-major. BM=128, BN=128, BK=128 bytes.
// 32x32x64 f8f6f4 MFMA, unit scales. 4 waves as 2x2, each 2x2 tiles of 32x32.
__launch_bounds__(256, 2)
__global__ void gemm_a8(const u8* __restrict__ A, const u8* __restrict__ B,
                        int ksteps, float* __restrict__ part){
  __shared__ u8 ldsA[128*128];
  __shared__ u8 ldsB[128*128];
  const int tid = threadIdx.x;
  const int m0  = blockIdx.x * 128;
  const int kch = blockIdx.z;
  const int kbase = kch * ksteps * 128;
  const int wave = tid >> 6, lane = tid & 63;
  const int l31 = lane & 31, half = lane >> 5;
  const int wm = wave >> 1, wn = wave & 1;

  f32x16 acc[2][2];
  #pragma unroll
  for (int mt=0; mt<2; ++mt)
    #pragma unroll
    for (int nt=0; nt<2; ++nt)
      #pragma unroll
      for (int r=0; r<16; ++r)
        acc[mt][nt][r] = 0.f;

  #pragma unroll 1
  for (int it=0; it<ksteps; ++it){
    const int k0 = kbase + it*128;
    // stage A tile: 128 rows x 128 B (8 chunks of 16B, XOR-8 swizzle)
    #pragma unroll
    for (int r=0; r<4; ++r){
      int cid = r*256 + tid;
      int row = cid >> 3, cph = cid & 7;
      int cgl = cph ^ (row & 7);
      async16(&ldsA[cid*16], A + (size_t)(m0+row)*16384 + (k0 + cgl*16));
    }
    // stage B tile: 128 rows x 128 B
    #pragma unroll
    for (int r=0; r<4; ++r){
      int cid = r*256 + tid;
      int row = cid >> 3, cph = cid & 7;
      int cgl = cph ^ (row & 7);
      async16(&ldsB[cid*16], B + (size_t)row*16384 + (k0 + cgl*16));
    }
    __syncthreads();
    #pragma unroll
    for (int s=0; s<2; ++s){          // two K=64 MFMA steps within BK=128
      const int lc = s*4 + half*2;    // logical 16B-chunk base for this lane's k-range
      i32x8 af[2], bg[2];
      #pragma unroll
      for (int mt=0; mt<2; ++mt){
        int am = wm*64 + mt*32 + l31;
        int c0 = (lc  ) ^ (am & 7);
        int c1 = (lc+1) ^ (am & 7);
        int4 lo = *(const int4*)&ldsA[am*128 + c0*16];
        int4 hi = *(const int4*)&ldsA[am*128 + c1*16];
        af[mt] = i32x8{lo.x, lo.y, lo.z, lo.w, hi.x, hi.y, hi.z, hi.w};
      }
      #pragma unroll
      for (int nt=0; nt<2; ++nt){
        int bn = wn*64 + nt*32 + l31;
        int c0 = (lc  ) ^ (bn & 7);
        int c1 = (lc+1) ^ (bn & 7);
        int4 lo = *(const int4*)&ldsB[bn*128 + c0*16];
        int4 hi = *(const int4*)&ldsB[bn*128 + c1*16];
        bg[nt] = i32x8{lo.x, lo.y, lo.z, lo.w, hi.x, hi.y, hi.z, hi.w};
      }
      #pragma unroll
      for (int mt=0; mt<2; ++mt)
        #pragma unroll
        for (int nt=0; nt<2; ++nt)
          acc[mt][nt] = __builtin_amdgcn_mfma_scale_f32_32x32x64_f8f6f4(
              af[mt], bg[nt], acc[mt][nt], 0, 0, 0, 0x7F7F7F7F, 0, 0x7F7F7F7F);
    }
    __syncthreads();
  }

  // epilogue: C/D 32x32 layout: col=lane&31, row=(reg&3)+8*(reg>>2)+4*half. Scale by 2^-16.
  float* outp = part + (size_t)kch * (8192*128);
  #pragma unroll
  for (int mt=0; mt<2; ++mt){
    int ib = m0 + wm*64 + mt*32 + 4*half;
    #pragma unroll
    for (int nt=0; nt<2; ++nt){
      int j = wn*64 + nt*32 + l31;
      #pragma unroll
      for (int reg=0; reg<16; ++reg){
        int ri = (reg & 3) + 8*(reg >> 2);
        outp[(size_t)(ib+ri)*128 + j] = acc[mt][nt][reg] * 0x1p-16f;
      }
    }
  }
}

// ---------------- per-step elementwise update ----------------
__global__ void step_update(const float* __restrict__ part, const float* __restrict__ Y,
                            const float* __restrict__ Y0, const float* __restrict__ UP,
                            const float* __restrict__ dbt, const float* __restrict__ dgt,
                            const float* __restrict__ qv,
                            float* __restrict__ Yn, u16* __restrict__ Ybn){
  int idx = blockIdx.x*256 + threadIdx.x;      // 262144 float4 groups
  int e = idx*4;
  int i = e >> 7, j = e & 127;
  f32x4 g = *(const f32x4*)(part + e);
  #pragma unroll
  for (int c=1; c<8; ++c)
    g += *(const f32x4*)(part + (size_t)c*1048576 + e);
  f32x4 y  = *(const f32x4*)(Y  + e);
  f32x4 y0 = *(const f32x4*)(Y0 + e);
  f32x4 u1 = *(const f32x4*)(UP + (size_t)i*256 + j);
  f32x4 u2 = *(const f32x4*)(UP + (size_t)i*256 + 128 + j);
  float db = LAM0*dbt[i], dg = LAM1*dgt[i], qi = qv[i];
  f32x4 yh = g + y0 + dg*y - (db*u1 + dg*u2);
  f32x4 yn = (1.0f-ALPHA_F)*y + (ALPHA_F*qi)*yh;
  *(f32x4*)(Yn + e) = yn;
  ushort4 pk;
  pk.x = f2bfu(yn[0]); pk.y = f2bfu(yn[1]); pk.z = f2bfu(yn[2]); pk.w = f2bfu(yn[3]);
  *(ushort4*)(Ybn + e) = pk;
}

// ---------------- classifier head: relu(Y) @ W2^T + b2 ----------------
__global__ void final_out(const float* __restrict__ Y, const float* __restrict__ W2,
                          const float* __restrict__ b2, float* __restrict__ out){
  int g = blockIdx.x*256 + threadIdx.x;
  if (g >= 8192*40) return;
  int i = g / 40, c = g - i*40;
  const float* yr = Y + (size_t)i*128;
  const float* wr = W2 + c*128;
  float s = 0.f;
  #pragma unroll 8
  for (int k=0; k<128; k+=4){
    f32x4 yv = *(const f32x4*)(yr+k);
    f32x4 wv = *(const f32x4*)(wr+k);
    s += fmaxf(yv[0],0.f)*wv[0] + fmaxf(yv[1],0.f)*wv[1]
       + fmaxf(yv[2],0.f)*wv[2] + fmaxf(yv[3],0.f)*wv[3];
  }
  out[g] = s + b2[c];
}

extern "C" void kernel_launch(void* const* d_in, const int* in_sizes, int n_in,
                              void* d_out, int out_size, void* d_ws, size_t ws_size,
                              hipStream_t stream){
  const float* x  = (const float*)d_in[0];
  const float* Ab = (const float*)d_in[1];
  const float* Ag = (const float*)d_in[2];
  const float* db = (const float*)d_in[3];
  const float* dg = (const float*)d_in[4];
  const float* H1 = (const float*)d_in[5];
  const float* H2 = (const float*)d_in[6];
  const float* W1 = (const float*)d_in[7];
  const float* b1 = (const float*)d_in[8];
  const float* W2 = (const float*)d_in[9];
  const float* b2 = (const float*)d_in[10];
  float* out = (float*)d_out;

  char* w = (char*)d_ws;
  size_t off = 0;
  auto take = [&](size_t bytes){ void* p = w + off; off += (bytes + 255) & ~(size_t)255; return p; };
  u8*    Acat8 = (u8*)   take((size_t)8192*16384);      // 128 MiB
  u8*    Ucat8 = (u8*)   take((size_t)128*16384);       // 2 MiB
  float* UPf   = (float*)take((size_t)8192*256*4);      // 8 MiB
  float* part  = (float*)take((size_t)8*8192*128*4);    // 32 MiB
  float* Y0f   = (float*)take((size_t)8192*128*4);
  float* Ya    = (float*)take((size_t)8192*128*4);
  float* Yb    = (float*)take((size_t)8192*128*4);
  u16*   Ybf0  = (u16*)  take((size_t)8192*128*2);
  u16*   Ybfa  = (u16*)  take((size_t)8192*128*2);
  u16*   Ybfb  = (u16*)  take((size_t)8192*128*2);
  u16*   xbf   = (u16*)  take((size_t)8192*512*2);
  u16*   BsT   = (u16*)  take((size_t)512*128*2);
  u16*   W1bf  = (u16*)  take((size_t)128*512*2);
  float* qinv  = (float*)take((size_t)8192*4);
  if (off > ws_size) return;  // workspace too small -> fail visibly

  // ---- one-time prep ----
  prep_bsmall<<<512, 128, 0, stream>>>(H1, H2, BsT);
  qinv_kernel<<<32, 256, 0, stream>>>(db, dg, qinv);
  cast_simple<<<256, 256, 0, stream>>>(W1, W1bf, 128*512);
  cast_simple<<<16384, 256, 0, stream>>>(x, xbf, 8192*512);
  cast_acat8<<<32768, 256, 0, stream>>>(Ab, Ag, Acat8);

  // Y0 = relu(x @ W1^T + b1): M=8192,K=512,N=128
  gemm_bf16<1,4,2,2,1><<<dim3(256,1,1), 256, 0, stream>>>(xbf, 512, W1bf, 512, 8, Y0f, Ybf0, nullptr, b1);

  const float* Yc = Y0f; const u16* Ybc = Ybf0;
  for (int s=0; s<8; ++s){
    // U = Y @ [S1'|S2'|P1|P2]: M=8192,K=128,N=512 -> Ucat8 (fp8) + UPf (fp32)
    gemm_bf16<2,2,2,4,2><<<dim3(128,4,1), 256, 0, stream>>>(Ybc, 128, BsT, 128, 2, UPf, nullptr, Ucat8, nullptr);
    // G1+G2 = (Acat8 @ Ucat8) * 2^-16: M=8192,K=16384,N=128, K-split 8
    gemm_a8<<<dim3(64,1,8), 256, 0, stream>>>(Acat8, Ucat8, 16, part);
    float* Yn  = (s & 1) ? Yb   : Ya;
    u16*   Ybn = (s & 1) ? Ybfb : Ybfa;
    step_update<<<1024, 256, 0, stream>>>(part, Yc, Y0f, UPf, db, dg, qinv, Yn, Ybn);
    Yc = Yn; Ybc = Ybn;
  }
  final_out<<<1280, 256, 0, stream>>>(Yc, W2, b2, out);
}

// Round 3
// 956.936 us; speedup vs baseline: 1.4715x; 1.0123x over previous
//
#include <hip/hip_runtime.h>
#include <hip/hip_bf16.h>
#include <stdint.h>

#define LAM0 1.0f
#define LAM1 1.0f
#define ALPHA_F (1.0f/3.0f)

typedef unsigned short u16;
typedef unsigned char u8;
typedef __attribute__((ext_vector_type(4))) float f32x4;
typedef __attribute__((ext_vector_type(16))) float f32x16;
typedef __attribute__((ext_vector_type(8))) __bf16 bf16x8;
typedef __attribute__((ext_vector_type(8))) int i32x8;

__device__ __forceinline__ u16 f2bfu(float f){
  union { __hip_bfloat16 h; u16 u; } cv;
  cv.h = __float2bfloat16(f);   // RNE
  return cv.u;
}

// pack 4 floats -> 4 fp8 e4m3 bytes (HW cvt, RNE)
__device__ __forceinline__ unsigned int pk4_fp8(float a, float b, float c, float d){
  int w = 0;
  w = __builtin_amdgcn_cvt_pk_fp8_f32(a, b, w, false);  // bytes 0,1
  w = __builtin_amdgcn_cvt_pk_fp8_f32(c, d, w, true);   // bytes 2,3
  return (unsigned int)w;
}

// async global->LDS, 16B per lane (wave-uniform base + lane*16 placement)
__device__ __forceinline__ void async16(void* lds, const void* g){
  __builtin_amdgcn_global_load_lds((const __attribute__((address_space(1))) void*)g,
                                   (__attribute__((address_space(3))) void*)lds, 16, 0, 0);
}

// ---------------- prep kernels ----------------
__global__ void prep_bsmall(const float* __restrict__ H1, const float* __restrict__ H2,
                            u16* __restrict__ BsT){
  int np = blockIdx.x;       // 0..511
  int k  = threadIdx.x;      // 0..127
  float v;
  if (np < 128){
    v = LAM0*(H1[k*128+np] + H1[np*128+k]);
  } else if (np < 256){
    int j = np-128;
    v = LAM1*(H2[k*128+j] + H2[j*128+k] - (k==j ? 1.0f : 0.0f));
  } else if (np < 384){
    int j = np-256; float s = 0.f;
    for (int q=0;q<128;++q) s += H1[k*128+q]*H1[j*128+q];
    v = s;
  } else {
    int j = np-384; float s = 0.f;
    for (int q=0;q<128;++q) s += H2[k*128+q]*H2[j*128+q];
    v = s;
  }
  BsT[np*128+k] = f2bfu(v);
}

__global__ void qinv_kernel(const float* __restrict__ db, const float* __restrict__ dg,
                            float* __restrict__ q){
  int i = blockIdx.x*256 + threadIdx.x;
  if (i < 8192) q[i] = 1.0f/(LAM0*db[i] + LAM1*dg[i] + 1.0f);
}

__global__ void cast_simple(const float* __restrict__ s, u16* __restrict__ d, int n){
  int i = blockIdx.x*256 + threadIdx.x;
  if (i < n) d[i] = f2bfu(s[i]);
}

// Acat8: 8192 x 16384 fp8, row i = [A_beta[i,:] | A_gamma[i,:]] * 2^16
// 32 elements per thread
__global__ void cast_acat8(const float* __restrict__ Ab, const float* __restrict__ Ag,
                           u8* __restrict__ Acat){
  size_t o = ((size_t)blockIdx.x*256 + threadIdx.x)*32;
  size_t i = o >> 14;
  int k = (int)(o & 16383);
  const float* src = (k < 8192) ? (Ab + i*8192 + k) : (Ag + i*8192 + (k - 8192));
  const float S = 65536.0f;
  uint4 p0, p1;
  {
    f32x4 v0 = *(const f32x4*)(src +  0);
    f32x4 v1 = *(const f32x4*)(src +  4);
    f32x4 v2 = *(const f32x4*)(src +  8);
    f32x4 v3 = *(const f32x4*)(src + 12);
    f32x4 v4 = *(const f32x4*)(src + 16);
    f32x4 v5 = *(const f32x4*)(src + 20);
    f32x4 v6 = *(const f32x4*)(src + 24);
    f32x4 v7 = *(const f32x4*)(src + 28);
    p0.x = pk4_fp8(v0[0]*S, v0[1]*S, v0[2]*S, v0[3]*S);
    p0.y = pk4_fp8(v1[0]*S, v1[1]*S, v1[2]*S, v1[3]*S);
    p0.z = pk4_fp8(v2[0]*S, v2[1]*S, v2[2]*S, v2[3]*S);
    p0.w = pk4_fp8(v3[0]*S, v3[1]*S, v3[2]*S, v3[3]*S);
    p1.x = pk4_fp8(v4[0]*S, v4[1]*S, v4[2]*S, v4[3]*S);
    p1.y = pk4_fp8(v5[0]*S, v5[1]*S, v5[2]*S, v5[3]*S);
    p1.z = pk4_fp8(v6[0]*S, v6[1]*S, v6[2]*S, v6[3]*S);
    p1.w = pk4_fp8(v7[0]*S, v7[1]*S, v7[2]*S, v7[3]*S);
  }
  *(uint4*)(Acat + o)      = p0;
  *(uint4*)(Acat + o + 16) = p1;
}

// ---------------- generic bf16 MFMA GEMM (small GEMMs) ----------------
template<int WM, int WN, int MT, int NT, int EPI>
__launch_bounds__(256, 2)
__global__ void gemm_bf16(const u16* __restrict__ A, int ldA,
                          const u16* __restrict__ B, int ldB,
                          int ksteps,
                          float* __restrict__ out0,
                          u16* __restrict__ outbf,
                          u8* __restrict__ out8,
                          const float* __restrict__ bias){
  constexpr int BM = WM*MT*16;
  constexpr int BN = WN*NT*16;
  __shared__ u16 ldsA[BM*64];
  __shared__ u16 ldsB[BN*64];
  const int tid  = threadIdx.x;
  const int m0   = blockIdx.x * BM;
  const int n0   = blockIdx.y * BN;
  const int wave = tid >> 6, lane = tid & 63;
  const int l15 = lane & 15, quad = lane >> 4;
  const int wm = wave / WN, wn = wave % WN;

  f32x4 acc[MT][NT];
  #pragma unroll
  for (int mt=0; mt<MT; ++mt)
    #pragma unroll
    for (int nt=0; nt<NT; ++nt)
      acc[mt][nt] = f32x4{0.f,0.f,0.f,0.f};

  #pragma unroll 1
  for (int it=0; it<ksteps; ++it){
    const int k0 = it*64;
    #pragma unroll
    for (int r=0; r<BM/32; ++r){
      int cid = r*256 + tid;
      int row = cid >> 3, cph = cid & 7;
      int cgl = cph ^ (row & 7);
      async16(&ldsA[cid*8], A + (size_t)(m0+row)*ldA + (k0 + cgl*8));
    }
    #pragma unroll
    for (int r=0; r<BN/32; ++r){
      int cid = r*256 + tid;
      int row = cid >> 3, cph = cid & 7;
      int cgl = cph ^ (row & 7);
      async16(&ldsB[cid*8], B + (size_t)(n0+row)*ldB + (k0 + cgl*8));
    }
    __syncthreads();
    #pragma unroll
    for (int kk=0; kk<2; ++kk){
      bf16x8 af[MT], bg[NT];
      #pragma unroll
      for (int mt=0; mt<MT; ++mt){
        int am = wm*MT*16 + mt*16 + l15;
        int cph = (kk*4 + quad) ^ (am & 7);
        af[mt] = *(const bf16x8*)&ldsA[am*64 + cph*8];
      }
      #pragma unroll
      for (int nt=0; nt<NT; ++nt){
        int bn = wn*NT*16 + nt*16 + l15;
        int cph = (kk*4 + quad) ^ (bn & 7);
        bg[nt] = *(const bf16x8*)&ldsB[bn*64 + cph*8];
      }
      #pragma unroll
      for (int mt=0; mt<MT; ++mt)
        #pragma unroll
        for (int nt=0; nt<NT; ++nt)
          acc[mt][nt] = __builtin_amdgcn_mfma_f32_16x16x32_bf16(af[mt], bg[nt], acc[mt][nt], 0, 0, 0);
    }
    __syncthreads();
  }

  const int ibase = m0 + wm*MT*16;
  const int jbase = n0 + wn*NT*16;
  if constexpr (EPI == 1){
    #pragma unroll
    for (int mt=0; mt<MT; ++mt){
      int i0 = ibase + mt*16 + quad*4;
      #pragma unroll
      for (int nt=0; nt<NT; ++nt){
        int j = jbase + nt*16 + l15;
        float bj = bias[j];
        #pragma unroll
        for (int r=0; r<4; ++r){
          float v = acc[mt][nt][r] + bj;
          v = fmaxf(v, 0.0f);
          out0 [(size_t)(i0+r)*128 + j] = v;
          outbf[(size_t)(i0+r)*128 + j] = f2bfu(v);
        }
      }
    }
  } else {
    #pragma unroll
    for (int mt=0; mt<MT; ++mt){
      int i0 = ibase + mt*16 + quad*4;
      #pragma unroll
      for (int nt=0; nt<NT; ++nt){
        int jg = jbase + nt*16 + l15;
        if (jg < 256){
          int nn = jg & 127;
          size_t koff = (jg < 128) ? (size_t)0 : (size_t)8192;
          unsigned int pk = pk4_fp8(acc[mt][nt][0], acc[mt][nt][1], acc[mt][nt][2], acc[mt][nt][3]);
          *(unsigned int*)&out8[(size_t)nn*16384 + koff + i0] = pk;
        } else {
          #pragma unroll
          for (int r=0; r<4; ++r)
            out0[(size_t)(i0+r)*256 + (jg-256)] = acc[mt][nt][r];
        }
      }
    }
  }
}

// ---------------- big fp8 MX GEMM, double-buffered LDS ----------------
// part[kch] = (Acat8 @ Ucat8^T-rows) * 2^-16
// A: 8192 x 16384 fp8 row-major; B: 128 x 16384 fp8 n-major. BM=128, BN=128, BK=128 B.
// One __syncthreads per K-iter; loads for iter t+1 fly during compute of iter t.
__launch_bounds__(256, 2)
__global__ void gemm_a8(const u8* __restrict__ A, const u8* __restrict__ B,
                        int ksteps, float* __restrict__ part){
  __shared__ u8 ldsA[2][128*128];
  __shared__ u8 ldsB[2][128*128];
  const int tid = threadIdx.x;
  const int m0  = blockIdx.x * 128;
  const int kch = blockIdx.z;
  const int kbase = kch * ksteps * 128;
  const int wave = tid >> 6, lane = tid & 63;
  const int l31 = lane & 31, half = lane >> 5;
  const int wm = wave >> 1, wn = wave & 1;

  auto stage = [&](int buf, int it){
    const int k0 = kbase + it*128;
    #pragma unroll
    for (int r=0; r<4; ++r){
      int cid = r*256 + tid;
      int row = cid >> 3, cph = cid & 7;
      int cgl = cph ^ (row & 7);
      async16(&ldsA[buf][cid*16], A + (size_t)(m0+row)*16384 + (k0 + cgl*16));
    }
    #pragma unroll
    for (int r=0; r<4; ++r){
      int cid = r*256 + tid;
      int row = cid >> 3, cph = cid & 7;
      int cgl = cph ^ (row & 7);
      async16(&ldsB[buf][cid*16], B + (size_t)row*16384 + (k0 + cgl*16));
    }
  };

  f32x16 acc[2][2];
  #pragma unroll
  for (int mt=0; mt<2; ++mt)
    #pragma unroll
    for (int nt=0; nt<2; ++nt)
      #pragma unroll
      for (int r=0; r<16; ++r)
        acc[mt][nt][r] = 0.f;

  stage(0, 0);
  #pragma unroll 1
  for (int it=0; it<ksteps; ++it){
    __syncthreads();                 // drains loads into buf[it&1]; buf[(it+1)&1] free
    if (it+1 < ksteps) stage((it+1)&1, it+1);
    const u8* lA = ldsA[it&1];
    const u8* lB = ldsB[it&1];
    #pragma unroll
    for (int s=0; s<2; ++s){
      const int lc = s*4 + half*2;
      i32x8 af[2], bg[2];
      #pragma unroll
      for (int mt=0; mt<2; ++mt){
        int am = wm*64 + mt*32 + l31;
        int c0 = (lc  ) ^ (am & 7);
        int c1 = (lc+1) ^ (am & 7);
        int4 lo = *(const int4*)&lA[am*128 + c0*16];
        int4 hi = *(const int4*)&lA[am*128 + c1*16];
        af[mt] = i32x8{lo.x, lo.y, lo.z, lo.w, hi.x, hi.y, hi.z, hi.w};
      }
      #pragma unroll
      for (int nt=0; nt<2; ++nt){
        int bn = wn*64 + nt*32 + l31;
        int c0 = (lc  ) ^ (bn & 7);
        int c1 = (lc+1) ^ (bn & 7);
        int4 lo = *(const int4*)&lB[bn*128 + c0*16];
        int4 hi = *(const int4*)&lB[bn*128 + c1*16];
        bg[nt] = i32x8{lo.x, lo.y, lo.z, lo.w, hi.x, hi.y, hi.z, hi.w};
      }
      #pragma unroll
      for (int mt=0; mt<2; ++mt)
        #pragma unroll
        for (int nt=0; nt<2; ++nt)
          acc[mt][nt] = __builtin_amdgcn_mfma_scale_f32_32x32x64_f8f6f4(
              af[mt], bg[nt], acc[mt][nt], 0, 0, 0, 0x7F7F7F7F, 0, 0x7F7F7F7F);
    }
  }

  // C/D 32x32 layout: col=lane&31, row=(reg&3)+8*(reg>>2)+4*half. Scale by 2^-16.
  float* outp = part + (size_t)kch * (8192*128);
  #pragma unroll
  for (int mt=0; mt<2; ++mt){
    int ib = m0 + wm*64 + mt*32 + 4*half;
    #pragma unroll
    for (int nt=0; nt<2; ++nt){
      int j = wn*64 + nt*32 + l31;
      #pragma unroll
      for (int reg=0; reg<16; ++reg){
        int ri = (reg & 3) + 8*(reg >> 2);
        outp[(size_t)(ib+ri)*128 + j] = acc[mt][nt][reg] * 0x1p-16f;
      }
    }
  }
}

// ---------------- per-step elementwise update ----------------
__global__ void step_update(const float* __restrict__ part, const float* __restrict__ Y,
                            const float* __restrict__ Y0, const float* __restrict__ UP,
                            const float* __restrict__ dbt, const float* __restrict__ dgt,
                            const float* __restrict__ qv,
                            float* __restrict__ Yn, u16* __restrict__ Ybn){
  int idx = blockIdx.x*256 + threadIdx.x;      // 262144 float4 groups
  int e = idx*4;
  int i = e >> 7, j = e & 127;
  f32x4 g = *(const f32x4*)(part + e);
  #pragma unroll
  for (int c=1; c<8; ++c)
    g += *(const f32x4*)(part + (size_t)c*1048576 + e);
  f32x4 y  = *(const f32x4*)(Y  + e);
  f32x4 y0 = *(const f32x4*)(Y0 + e);
  f32x4 u1 = *(const f32x4*)(UP + (size_t)i*256 + j);
  f32x4 u2 = *(const f32x4*)(UP + (size_t)i*256 + 128 + j);
  float db = LAM0*dbt[i], dg = LAM1*dgt[i], qi = qv[i];
  f32x4 yh = g + y0 + dg*y - (db*u1 + dg*u2);
  f32x4 yn = (1.0f-ALPHA_F)*y + (ALPHA_F*qi)*yh;
  *(f32x4*)(Yn + e) = yn;
  ushort4 pk;
  pk.x = f2bfu(yn[0]); pk.y = f2bfu(yn[1]); pk.z = f2bfu(yn[2]); pk.w = f2bfu(yn[3]);
  *(ushort4*)(Ybn + e) = pk;
}

// ---------------- classifier head: relu(Y) @ W2^T + b2 ----------------
__global__ void final_out(const float* __restrict__ Y, const float* __restrict__ W2,
                          const float* __restrict__ b2, float* __restrict__ out){
  int g = blockIdx.x*256 + threadIdx.x;
  if (g >= 8192*40) return;
  int i = g / 40, c = g - i*40;
  const float* yr = Y + (size_t)i*128;
  const float* wr = W2 + c*128;
  float s = 0.f;
  #pragma unroll 8
  for (int k=0; k<128; k+=4){
    f32x4 yv = *(const f32x4*)(yr+k);
    f32x4 wv = *(const f32x4*)(wr+k);
    s += fmaxf(yv[0],0.f)*wv[0] + fmaxf(yv[1],0.f)*wv[1]
       + fmaxf(yv[2],0.f)*wv[2] + fmaxf(yv[3],0.f)*wv[3];
  }
  out[g] = s + b2[c];
}

extern "C" void kernel_launch(void* const* d_in, const int* in_sizes, int n_in,
                              void* d_out, int out_size, void* d_ws, size_t ws_size,
                              hipStream_t stream){
  const float* x  = (const float*)d_in[0];
  const float* Ab = (const float*)d_in[1];
  const float* Ag = (const float*)d_in[2];
  const float* db = (const float*)d_in[3];
  const float* dg = (const float*)d_in[4];
  const float* H1 = (const float*)d_in[5];
  const float* H2 = (const float*)d_in[6];
  const float* W1 = (const float*)d_in[7];
  const float* b1 = (const float*)d_in[8];
  const float* W2 = (const float*)d_in[9];
  const float* b2 = (const float*)d_in[10];
  float* out = (float*)d_out;

  char* w = (char*)d_ws;
  size_t off = 0;
  auto take = [&](size_t bytes){ void* p = w + off; off += (bytes + 255) & ~(size_t)255; return p; };
  u8*    Acat8 = (u8*)   take((size_t)8192*16384);      // 128 MiB
  u8*    Ucat8 = (u8*)   take((size_t)128*16384);       // 2 MiB
  float* UPf   = (float*)take((size_t)8192*256*4);      // 8 MiB
  float* part  = (float*)take((size_t)8*8192*128*4);    // 32 MiB
  float* Y0f   = (float*)take((size_t)8192*128*4);
  float* Ya    = (float*)take((size_t)8192*128*4);
  float* Yb    = (float*)take((size_t)8192*128*4);
  u16*   Ybf0  = (u16*)  take((size_t)8192*128*2);
  u16*   Ybfa  = (u16*)  take((size_t)8192*128*2);
  u16*   Ybfb  = (u16*)  take((size_t)8192*128*2);
  u16*   xbf   = (u16*)  take((size_t)8192*512*2);
  u16*   BsT   = (u16*)  take((size_t)512*128*2);
  u16*   W1bf  = (u16*)  take((size_t)128*512*2);
  float* qinv  = (float*)take((size_t)8192*4);
  if (off > ws_size) return;  // workspace too small -> fail visibly

  // ---- one-time prep ----
  prep_bsmall<<<512, 128, 0, stream>>>(H1, H2, BsT);
  qinv_kernel<<<32, 256, 0, stream>>>(db, dg, qinv);
  cast_simple<<<256, 256, 0, stream>>>(W1, W1bf, 128*512);
  cast_simple<<<16384, 256, 0, stream>>>(x, xbf, 8192*512);
  cast_acat8<<<16384, 256, 0, stream>>>(Ab, Ag, Acat8);

  // Y0 = relu(x @ W1^T + b1): M=8192,K=512,N=128
  gemm_bf16<1,4,2,2,1><<<dim3(256,1,1), 256, 0, stream>>>(xbf, 512, W1bf, 512, 8, Y0f, Ybf0, nullptr, b1);

  const float* Yc = Y0f; const u16* Ybc = Ybf0;
  for (int s=0; s<8; ++s){
    // U = Y @ [S1'|S2'|P1|P2]: M=8192,K=128,N=512 -> Ucat8 (fp8) + UPf (fp32)
    gemm_bf16<2,2,2,4,2><<<dim3(128,4,1), 256, 0, stream>>>(Ybc, 128, BsT, 128, 2, UPf, nullptr, Ucat8, nullptr);
    // G1+G2 = (Acat8 @ Ucat8) * 2^-16: M=8192,K=16384,N=128, K-split 8
    gemm_a8<<<dim3(64,1,8), 256, 0, stream>>>(Acat8, Ucat8, 16, part);
    float* Yn  = (s & 1) ? Yb   : Ya;
    u16*   Ybn = (s & 1) ? Ybfb : Ybfa;
    step_update<<<1024, 256, 0, stream>>>(part, Yc, Y0f, UPf, db, dg, qinv, Yn, Ybn);
    Yc = Yn; Ybc = Ybn;
  }
  final_out<<<1280, 256, 0, stream>>>(Yc, W2, b2, out);
}